// Round 2
// 299.365 us; speedup vs baseline: 1.0379x; 1.0379x over previous
//
#include <hip/hip_runtime.h>

#define L_HIST 2048
typedef unsigned short ushortT;
typedef __attribute__((ext_vector_type(8))) short bf16x8;
typedef __attribute__((ext_vector_type(4))) short bf16x4;
typedef __attribute__((ext_vector_type(16))) float f32x16;

__device__ __forceinline__ ushortT f2bf(float x) {
  union { float f; unsigned u; } v; v.f = x;
  unsigned r = (v.u + 0x7FFFu + ((v.u >> 16) & 1u)) >> 16;
  return (ushortT)r;
}
__device__ __forceinline__ float bf2f(ushortT h) {
  union { unsigned u; float f; } v; v.u = ((unsigned)h) << 16; return v.f;
}
__device__ __forceinline__ bf16x4 lo4(bf16x8 v) {
  return __builtin_shufflevector(v, v, 0, 1, 2, 3);
}
__device__ __forceinline__ bf16x4 hi4(bf16x8 v) {
  return __builtin_shufflevector(v, v, 4, 5, 6, 7);
}
__device__ __forceinline__ bf16x8 rd8(const ushortT* p) {
  bf16x4 a = *(const bf16x4*)p, b = *(const bf16x4*)(p + 4);
  return __builtin_shufflevector(a, b, 0, 1, 2, 3, 4, 5, 6, 7);
}

// ---------------- job-table mega kernel -------------------------------------
// Block ranges: [0,qbase) bf16 bt-GEMM jobs; [qbase,rbase) qgemm (W*U) blocks;
// [rbase,utbase) rgemm blocks; [utbase,grid) ut_gemv slices.
struct Job {
  const ushortT *Ph, *Qh, *Ql;
  ushortT *Ch, *Cl;
  float *Cf;
  int M, tbase;
};
struct Prm {
  Job j[3]; int nj;
  int qbase, rbase, utbase, uv0;
  const ushortT *Wt, *Uh, *Ul;
  float *Qp;
  const float *Pf1; float *Rp;
  const float *Mt, *Mbar, *wv; float *outp;
};

__global__ __launch_bounds__(256) void mega(Prm p) {
  __shared__ __align__(16) ushortT As[4][64][36];
  __shared__ ushortT Bhs[4][64][36];
  __shared__ ushortT Bls[4][64][36];
  int bx = blockIdx.x;
  int tid = threadIdx.x;

  if (bx >= p.utbase) {
    // ---- u_t gemv slice (hidden under latency-bound chain) ----
    int u = bx - p.utbase + p.uv0;
    int n = u & 255, h = u >> 8;
    int lane = tid & 63, wid = tid >> 6;
    int vs = (306 * h) >> 2, ve = (306 * (h + 1)) >> 2;
    float4 acc = {0.f, 0.f, 0.f, 0.f};
#pragma unroll 4
    for (int v = vs + wid; v < ve; v += 4) {
      const float* mat = (v < 17 ? p.Mbar : p.Mt - 17 * 65536) + (size_t)v * 65536;
      float4 mv = ((const float4*)(mat + (size_t)n * 256))[lane];
      float4 wv = ((const float4*)(p.wv + (size_t)v * 256))[lane];
      acc.x += mv.x * wv.x; acc.y += mv.y * wv.y;
      acc.z += mv.z * wv.z; acc.w += mv.w * wv.w;
    }
    float a = (acc.x + acc.y) + (acc.z + acc.w);
    for (int off = 32; off > 0; off >>= 1) a += __shfl_down(a, off);
    if (lane == 0) atomicAdd(&p.outp[512 + n], a);
    return;
  }

  if (bx >= p.rbase) {
    // ---- R partials, 256-thread variant (2 blocks per (j1,dc)) ----
    int r = bx - p.rbase;
    float* Qs = (float*)&As[0][0][0];   // reuse LDS as [128][8] fp32
    int pr = r >> 1, mh = r & 1;
    int j1 = (pr >> 2) + 1, dc = pr & 3;
    int d0 = dc * 128, m = mh * 256 + tid;
    for (int i = tid; i < 1024; i += 256) {
      int dd = i >> 3, jj = i & 7;
      float s = 0.f;
#pragma unroll
      for (int z = 0; z < 16; ++z)
        s += p.Qp[((size_t)z * 512 + d0 + dd) * 128 + j1 + 8 * jj];
      Qs[dd * 8 + jj] = s;
    }
    __syncthreads();
    float acc[8];
#pragma unroll
    for (int jj = 0; jj < 8; ++jj) acc[jj] = 0.f;
    for (int d = 0; d < 128; ++d) {
      float tv = p.Pf1[((size_t)(j1 - 1) * 512 + d0 + d) * 512 + m];
      float4 q0 = *(const float4*)&Qs[d * 8];
      float4 q1 = *(const float4*)&Qs[d * 8 + 4];
      acc[0] += tv * q0.x; acc[1] += tv * q0.y; acc[2] += tv * q0.z; acc[3] += tv * q0.w;
      acc[4] += tv * q1.x; acc[5] += tv * q1.y; acc[6] += tv * q1.z; acc[7] += tv * q1.w;
    }
    float* dst = p.Rp + (size_t)((j1 - 1) * 4 + dc) * 4096 + m * 8;
#pragma unroll
    for (int jj = 0; jj < 8; ++jj) dst[jj] = acc[jj];
    return;
  }

  if (bx >= p.qbase) {
    // ---- Q = W*U, z-split 16 (512-K slices), K-chunked 128 ----
    int q = bx - p.qbase;
    int z = q & 15, mtile = (q >> 4) & 7, ntile = q >> 7;
    int m0 = mtile * 64, n0 = ntile * 64, k0 = z * 512;
    int lane = tid & 63, wave = tid >> 6;
    int wm = (wave & 1) * 32, wn = (wave >> 1) * 32;
    int fr = lane & 31, fk = (lane >> 5) * 8;
    int ka = tid & 31, ma = (tid >> 5) * 8;
    int jb = tid >> 2, kb = (tid & 3) * 8;

    const ushortT* pW  = p.Wt + (size_t)(k0 + ka) * 512 + m0 + ma;
    const ushortT* pUh = p.Uh + (size_t)(n0 + jb) * 8192 + k0 + kb;
    const ushortT* pUl = p.Ul + (size_t)(n0 + jb) * 8192 + k0 + kb;

    bf16x8 rW[4], rUh[4], rUl[4];
#pragma unroll
    for (int s = 0; s < 4; ++s) {
      rW[s]  = *(const bf16x8*)(pW + (size_t)(s * 32) * 512);
      rUh[s] = *(const bf16x8*)(pUh + s * 32);
      rUl[s] = *(const bf16x8*)(pUl + s * 32);
    }
    f32x16 acc;
#pragma unroll
    for (int i = 0; i < 16; ++i) acc[i] = 0.f;

    for (int c = 0; c < 4; ++c) {
#pragma unroll
      for (int s = 0; s < 4; ++s) {
#pragma unroll
        for (int e = 0; e < 8; ++e) As[s][ma + e][ka] = (ushortT)rW[s][e];
        *(bf16x4*)&Bhs[s][jb][kb]     = lo4(rUh[s]);
        *(bf16x4*)&Bhs[s][jb][kb + 4] = hi4(rUh[s]);
        *(bf16x4*)&Bls[s][jb][kb]     = lo4(rUl[s]);
        *(bf16x4*)&Bls[s][jb][kb + 4] = hi4(rUl[s]);
      }
      __syncthreads();
      if (c < 3) {
        int off = (c + 1) * 128;
#pragma unroll
        for (int s = 0; s < 4; ++s) {
          rW[s]  = *(const bf16x8*)(pW + (size_t)(off + s * 32) * 512);
          rUh[s] = *(const bf16x8*)(pUh + off + s * 32);
          rUl[s] = *(const bf16x8*)(pUl + off + s * 32);
        }
      }
#pragma unroll
      for (int s = 0; s < 4; ++s)
#pragma unroll
        for (int ks = 0; ks < 32; ks += 16) {
          bf16x8 a  = rd8(&As[s][wm + fr][ks + fk]);
          bf16x8 bh = rd8(&Bhs[s][wn + fr][ks + fk]);
          bf16x8 bl = rd8(&Bls[s][wn + fr][ks + fk]);
          acc = __builtin_amdgcn_mfma_f32_32x32x16_bf16(a, bh, acc, 0, 0, 0);
          acc = __builtin_amdgcn_mfma_f32_32x32x16_bf16(a, bl, acc, 0, 0, 0);
        }
      __syncthreads();
    }
#pragma unroll
    for (int i = 0; i < 16; ++i) {
      int rr = wm + (i & 3) + ((i >> 2) << 3) + ((lane >> 5) << 2);
      int cc = wn + (lane & 31);
      p.Qp[((size_t)z * 512 + m0 + rr) * 128 + n0 + cc] = acc[i];
    }
    return;
  }

  // ---- dual-product bf16 bt-GEMM jobs: D[m][n]=sum_k Ph[m][k]*(Qh+Ql)[n][k]
  int ji = 0;
  if (p.nj > 1 && bx >= p.j[1].tbase) ji = 1;
  if (p.nj > 2 && bx >= p.j[2].tbase) ji = 2;
  Job J = p.j[ji];
  int lt = bx - J.tbase;
  int mt = J.M >> 6;
  int mtile = lt % mt, ntile = lt / mt;
  size_t m0 = (size_t)mtile * 64, n0 = (size_t)ntile * 64;

  int lane = tid & 63, wave = tid >> 6;
  int wm = (wave & 1) * 32, wn = (wave >> 1) * 32;
  int fr = lane & 31, fk = (lane >> 5) * 8;
  int row = tid >> 2, kp = (tid & 3) * 8;

  const ushortT* pA  = J.Ph + (m0 + row) * 512 + kp;
  const ushortT* pBh = J.Qh + (n0 + row) * 512 + kp;
  const ushortT* pBl = J.Ql + (n0 + row) * 512 + kp;

  bf16x8 rA[4], rBh[4], rBl[4];
#pragma unroll
  for (int s = 0; s < 4; ++s) {
    rA[s]  = *(const bf16x8*)(pA  + s * 32);
    rBh[s] = *(const bf16x8*)(pBh + s * 32);
    rBl[s] = *(const bf16x8*)(pBl + s * 32);
  }

  f32x16 acc;
#pragma unroll
  for (int i = 0; i < 16; ++i) acc[i] = 0.f;

  for (int c = 0; c < 4; ++c) {
#pragma unroll
    for (int s = 0; s < 4; ++s) {
      *(bf16x4*)&As[s][row][kp]      = lo4(rA[s]);
      *(bf16x4*)&As[s][row][kp + 4]  = hi4(rA[s]);
      *(bf16x4*)&Bhs[s][row][kp]     = lo4(rBh[s]);
      *(bf16x4*)&Bhs[s][row][kp + 4] = hi4(rBh[s]);
      *(bf16x4*)&Bls[s][row][kp]     = lo4(rBl[s]);
      *(bf16x4*)&Bls[s][row][kp + 4] = hi4(rBl[s]);
    }
    __syncthreads();
    if (c < 3) {
      int off = (c + 1) * 128;
#pragma unroll
      for (int s = 0; s < 4; ++s) {
        rA[s]  = *(const bf16x8*)(pA  + off + s * 32);
        rBh[s] = *(const bf16x8*)(pBh + off + s * 32);
        rBl[s] = *(const bf16x8*)(pBl + off + s * 32);
      }
    }
#pragma unroll
    for (int s = 0; s < 4; ++s)
#pragma unroll
      for (int ks = 0; ks < 32; ks += 16) {
        bf16x8 a  = rd8(&As[s][wm + fr][ks + fk]);
        bf16x8 bh = rd8(&Bhs[s][wn + fr][ks + fk]);
        bf16x8 bl = rd8(&Bls[s][wn + fr][ks + fk]);
        acc = __builtin_amdgcn_mfma_f32_32x32x16_bf16(a, bh, acc, 0, 0, 0);
        acc = __builtin_amdgcn_mfma_f32_32x32x16_bf16(a, bl, acc, 0, 0, 0);
      }
    __syncthreads();
  }
#pragma unroll
  for (int i = 0; i < 16; ++i) {
    int r = wm + (i & 3) + ((i >> 2) << 3) + ((lane >> 5) << 2);
    int c = wn + (lane & 31);
    float v = acc[i];
    size_t off = (m0 + r) * 512 + (n0 + c);
    ushortT h = f2bf(v);
    J.Ch[off] = h;
    if (J.Cl) J.Cl[off] = f2bf(v - bf2f(h));
    if (J.Cf) J.Cf[off] = v;
  }
}

// ---------------- fused init: split A, split B(hi), pack U, u_t weights -----
__global__ __launch_bounds__(256) void init_all(
    const float* __restrict__ A, const float* __restrict__ B,
    const float* __restrict__ uh,
    ushortT* N1h, ushortT* N1l, ushortT* T1h, ushortT* T1l,
    ushortT* WTh, ushortT* UTh, ushortT* UTl,
    const float* __restrict__ ynh, const float* __restrict__ sigma,
    const float* __restrict__ phi, const float* __restrict__ lambda_e,
    const float* __restrict__ phi_tilde, float* __restrict__ wvec,
    float* __restrict__ out) {
  __shared__ float w4[48];
  if (blockIdx.x >= 5632) {
    // ---- u_t weight vectors (former weights_kernel, verified R1-R5) ----
    int v = blockIdx.x - 5632;
    int p = threadIdx.x;
    float val = 0.f;
    if (v == 0) {
      val = ynh[(size_t)(L_HIST - 1) * 256 + p];
      out[512 + p] = 0.f;
    } else if (v <= 16) {
      int i = v - 1;
      float s = 0.f;
      for (int j = 0; j < 24; ++j)
        s += phi_tilde[j * 16 + i] * ynh[(size_t)(L_HIST - 2 - j) * 256 + p];
      val = powf(lambda_e[i], 0.25f) * s;
    } else if (v <= 33) {
      int l = v - 17;
      float s = 0.f;
      for (int k = 0; k < 25; ++k)
        s += phi[k * 17 + l] * ynh[(size_t)(L_HIST - 1 - k) * 256 + p];
      val = powf(sigma[l], 0.25f) * s;
    } else {
      int t = v - 34;
      int i = t / 17, l = t % 17;
      if (p < 48) {
        int m = p;
        int jlo = m - 24; if (jlo < 0) jlo = 0;
        int jhi = m; if (jhi > 23) jhi = 23;
        float s = 0.f;
        for (int j = jlo; j <= jhi; ++j)
          s += phi_tilde[j * 16 + i] * phi[(m - j) * 17 + l];
        w4[p] = s;
      }
      __syncthreads();
      float s = 0.f;
      for (int m = 0; m < 48; ++m)
        s += w4[m] * ynh[(size_t)(L_HIST - 3 - m) * 256 + p];
      val = powf(lambda_e[i], 0.25f) * powf(sigma[l], 0.25f) * s;
    }
    wvec[v * 256 + p] = val;
    return;
  }
  int idx = blockIdx.x * 256 + threadIdx.x;
  if (idx < 262144) {
    int r = idx >> 9, c = idx & 511;
    float x = A[idx];
    ushortT h = f2bf(x); ushortT l = f2bf(x - bf2f(h));
    N1h[idx] = h; N1l[idx] = l;
    T1h[c * 512 + r] = h; T1l[c * 512 + r] = l;
  } else if (idx < 262144 + 131072) {
    int i2 = idx - 262144;
    int d = i2 >> 8, c = i2 & 255;
    WTh[c * 512 + d] = f2bf(B[i2]);
  } else {
    int i2 = idx - 393216;          // < 128*8192
    int j = i2 >> 13, k = i2 & 8191;
    int tau = k >> 8, c = k & 255;
    float v = 0.f;
    if (j < 64) v = uh[(size_t)(L_HIST - 1 - (32 * j + tau)) * 256 + c];
    else if (j == 64 && tau < 16) v = uh[(size_t)(L_HIST - 1 - tau) * 256 + c];
    ushortT h = f2bf(v);
    UTh[i2] = h; UTl[i2] = f2bf(v - bf2f(h));
  }
}

// ---------------- S partials (assembles Rb rows inline), z=16 ---------------
__global__ __launch_bounds__(512) void sgemm(const float* __restrict__ Pf2,
                                             const float* __restrict__ Qpart,
                                             const float* __restrict__ Rpart,
                                             float* __restrict__ Spart) {
  int j2 = blockIdx.x + 1;     // 1..7
  int dc = blockIdx.y;         // 0..3
  int d0 = dc * 128;
  int m = threadIdx.x;
  __shared__ float Rs[128];
  if (threadIdx.x < 128) {
    int dd = threadIdx.x;
    float s = 0.f;
#pragma unroll
    for (int z = 0; z < 16; ++z)
      s += Qpart[((size_t)z * 512 + d0 + dd) * 128 + 8 * j2];
    for (int p = 0; p < 28; ++p)
      s += Rpart[(size_t)p * 4096 + (d0 + dd) * 8 + j2];
    Rs[dd] = s;
  }
  __syncthreads();
  float acc = 0.f;
  for (int d = 0; d < 128; ++d)
    acc += Pf2[((size_t)(j2 - 1) * 512 + d0 + d) * 512 + m] * Rs[d];
  Spart[(size_t)((j2 - 1) * 4 + dc) * 512 + m] = acc;
}

// ---------------- finalize: y_nat & pred (assembles s inline), z=16 ---------
__global__ __launch_bounds__(64) void finalize_kernel(
    const float* __restrict__ Cmat, const float* __restrict__ Qpart,
    const float* __restrict__ Rpart, const float* __restrict__ Spart,
    const float* __restrict__ yh, float* __restrict__ out) {
  int p = blockIdx.x;
  int lane = threadIdx.x;
  float a1 = 0.f, a2 = 0.f;
  for (int t = lane; t < 512; t += 64) {
    float sb = 0.f, qp = 0.f;
#pragma unroll
    for (int z = 0; z < 16; ++z) {
      sb += Qpart[((size_t)z * 512 + t) * 128 + 0];
      qp += Qpart[((size_t)z * 512 + t) * 128 + 64];
    }
    for (int q = 0; q < 28; ++q) {
      sb += Rpart[(size_t)q * 4096 + t * 8];
      sb += Spart[(size_t)q * 512 + t];
    }
    float cv = Cmat[(size_t)p * 512 + t];
    a1 += cv * sb;
    a2 += cv * qp;
  }
  for (int off = 32; off > 0; off >>= 1) {
    a1 += __shfl_down(a1, off);
    a2 += __shfl_down(a2, off);
  }
  if (lane == 0) {
    float ynat = yh[(size_t)(L_HIST - 1) * 256 + p] - a1;
    out[p] = ynat;
    out[256 + p] = ynat + a2;
  }
}

// ---------------- host orchestration ----------------------------------------
extern "C" void kernel_launch(void* const* d_in, const int* in_sizes, int n_in,
                              void* d_out, int out_size, void* d_ws, size_t ws_size,
                              hipStream_t stream) {
  (void)in_sizes; (void)n_in; (void)out_size; (void)ws_size;
  const float* A   = (const float*)d_in[0];
  const float* B   = (const float*)d_in[1];
  const float* C   = (const float*)d_in[2];
  const float* M   = (const float*)d_in[3];
  const float* Mb  = (const float*)d_in[4];
  const float* sig = (const float*)d_in[5];
  const float* phi = (const float*)d_in[6];
  const float* lam = (const float*)d_in[7];
  const float* pt  = (const float*)d_in[8];
  const float* yh  = (const float*)d_in[9];
  const float* uh  = (const float*)d_in[10];
  const float* ynh = (const float*)d_in[11];
  float* out = (float*)d_out;
  char* base = (char*)d_ws;

  // compact layout, 0.5MB granularity; total < 61MB (round-0 proven ~64.8MB)
  const size_t HMB = 512u * 1024u;
  const size_t SL = 512 * 512;            // elems per 512x512 plane
  ushortT* POW  = (ushortT*)base;                  // 16 slots x (hi+lo) = 16MB
  ushortT* WTh  = (ushortT*)(base + 32 * HMB);     // 8192x512  (8MB)
  ushortT* P1th = (ushortT*)(base + 48 * HMB);     // 7 x SL    (3.5MB)
  ushortT* P1tl = (ushortT*)(base + 55 * HMB);
  ushortT* P2th = (ushortT*)(base + 62 * HMB);
  ushortT* P2tl = (ushortT*)(base + 69 * HMB);
  float*   Pf1  = (float*)(base + 76 * HMB);       // 7 x SL fp32 (7MB)
  float*   Pf2  = (float*)(base + 90 * HMB);
  ushortT* UTh  = (ushortT*)(base + 104 * HMB);    // 128x8192 (2MB)
  ushortT* UTl  = (ushortT*)(base + 108 * HMB);
  float*   Qpart= (float*)(base + 112 * HMB);      // 16x512x128 fp32 (4MB)
  float*   Rpart= (float*)(base + 120 * HMB);      // 28x4096
  float*   Spart= Rpart + 28 * 4096;               // 28x512
  float*   wvec = Spart + 28 * 512;                // 306x256

  auto ph = [&](int i) { return POW + (size_t)i * 2 * SL; };
  auto pl = [&](int i) { return POW + (size_t)i * 2 * SL + SL; };
  // slots: 0:N1 1:T1 2:N2 3:T2 4:N4 5:T4 6:N8 7:T8 8:N16 9:T16
  //        10:N32 11:N64 12:N128 13:N256 14:N512 15:N1024
  auto e1h = [&](int j) { return P1th + (size_t)(j - 1) * SL; };
  auto e1l = [&](int j) { return P1tl + (size_t)(j - 1) * SL; };
  auto e2h = [&](int j) { return P2th + (size_t)(j - 1) * SL; };
  auto e2l = [&](int j) { return P2tl + (size_t)(j - 1) * SL; };

  auto mkJ = [&](const ushortT* Ph, const ushortT* Qh, const ushortT* Ql,
                 ushortT* Ch, ushortT* Cl, float* Cf, int Mrows) {
    Job j; j.Ph = Ph; j.Qh = Qh; j.Ql = Ql;
    j.Ch = Ch; j.Cl = Cl; j.Cf = Cf; j.M = Mrows; j.tbase = 0; return j;
  };
  int uvoff = 0;
  auto runL = [&](Job j0, Job j1, Job j2, int nj, int qcnt, int rcnt, int utcnt) {
    Prm p; p.j[0] = j0; p.j[1] = (nj > 1) ? j1 : j0; p.j[2] = (nj > 2) ? j2 : j0;
    p.nj = nj;
    int tb = 0;
    for (int i = 0; i < nj; ++i) { p.j[i].tbase = tb; tb += (p.j[i].M >> 6) * 8; }
    p.qbase = tb; p.rbase = tb + qcnt; p.utbase = p.rbase + rcnt;
    p.uv0 = uvoff; uvoff += utcnt;
    p.Wt = WTh; p.Uh = UTh; p.Ul = UTl; p.Qp = Qpart;
    p.Pf1 = Pf1; p.Rp = Rpart;
    p.Mt = M; p.Mbar = Mb; p.wv = wvec; p.outp = out;
    mega<<<p.utbase + utcnt, 256, 0, stream>>>(p);
  };

  // ---- init + u_t weights (one node; weights feed the ut slices below) ----
  init_all<<<5938, 256, 0, stream>>>(A, B, uh, ph(0), pl(0), ph(1), pl(1),
                                     WTh, UTh, UTl,
                                     ynh, sig, phi, lam, pt, wvec, out);

  Job d = mkJ(ph(0), ph(1), pl(1), ph(2), pl(2), nullptr, 512); // dummy
  // ---- dual power/W/stack chain: 11 launches, ut slices spread across all,
  //      qgemm blocks ride L6 (WTh done after L5), rgemm rides L9 (Pf1 done L8)
  runL(mkJ(ph(0), ph(1), pl(1), ph(2), pl(2), nullptr, 512),              // N2
       mkJ(ph(1), ph(0), pl(0), ph(3), pl(3), nullptr, 512),              // T2
       mkJ(WTh, ph(0), pl(0), WTh + 256 * 512, nullptr, nullptr, 256),    // W1
       3, 0, 0, 93);
  runL(mkJ(ph(2), ph(3), pl(3), ph(4), pl(4), nullptr, 512),              // N4
       mkJ(ph(3), ph(2), pl(2), ph(5), pl(5), nullptr, 512),              // T4
       mkJ(WTh, ph(2), pl(2), WTh + 512 * 512, nullptr, nullptr, 512),    // W2:4
       3, 0, 0, 93);
  runL(mkJ(ph(4), ph(5), pl(5), ph(6), pl(6), nullptr, 512),              // N8
       mkJ(ph(5), ph(4), pl(4), ph(7), pl(7), nullptr, 512),              // T8
       mkJ(WTh, ph(4), pl(4), WTh + 1024 * 512, nullptr, nullptr, 1024),  // W4:8
       3, 0, 0, 93);
  runL(mkJ(ph(6), ph(7), pl(7), ph(8), pl(8), nullptr, 512),              // N16
       mkJ(ph(7), ph(6), pl(6), ph(9), pl(9), nullptr, 512),              // T16
       mkJ(WTh, ph(6), pl(6), WTh + 2048 * 512, nullptr, nullptr, 2048),  // W8:16
       3, 0, 0, 93);
  runL(mkJ(ph(8), ph(9), pl(9), ph(10), pl(10), nullptr, 512),            // N32
       mkJ(ph(9), ph(8), pl(8), e1h(1), e1l(1), Pf1, 512),                // T32
       mkJ(WTh, ph(8), pl(8), WTh + 4096 * 512, nullptr, nullptr, 4096),  // W16:32
       3, 0, 0, 93);
  runL(mkJ(ph(10), e1h(1), e1l(1), ph(11), pl(11), nullptr, 512),         // N64
       mkJ(e1h(1), ph(10), pl(10), e1h(2), e1l(2), Pf1 + SL, 512),        // T64
       d, 2, 256, 0, 93);                                                 // + qgemm
  runL(mkJ(ph(11), e1h(2), e1l(2), ph(12), pl(12), nullptr, 512),         // N128
       mkJ(e1h(1), ph(11), pl(11), e1h(3), e1l(3), Pf1 + 2 * SL, 1024),   // T96,T128
       d, 2, 0, 0, 93);
  runL(mkJ(ph(12), e1h(4), e1l(4), ph(13), pl(13), nullptr, 512),         // N256
       mkJ(e1h(1), ph(12), pl(12), e1h(5), nullptr, Pf1 + 4 * SL, 1536),  // T160..224
       mkJ(e1h(4), ph(12), pl(12), e2h(1), e2l(1), Pf2, 512),             // T256
       3, 0, 0, 93);
  runL(mkJ(ph(13), e2h(1), e2l(1), ph(14), pl(14), nullptr, 512),         // N512
       mkJ(e2h(1), ph(13), pl(13), e2h(2), e2l(2), Pf2 + SL, 512),        // T512
       d, 2, 0, 56, 93);                                                  // + rgemm
  runL(mkJ(ph(14), e2h(2), e2l(2), ph(15), pl(15), nullptr, 512),         // N1024
       mkJ(e2h(1), ph(14), pl(14), e2h(3), nullptr, Pf2 + 2 * SL, 1024),  // T768,T1024
       d, 2, 0, 0, 93);
  runL(mkJ(e2h(1), ph(15), pl(15), e2h(5), nullptr, Pf2 + 4 * SL, 1536),  // T1280..1792
       d, d, 1, 0, 0, 94);

  // ---- tail: S partials need Pf2 planes from L11; finalize needs Spart ----
  sgemm<<<dim3(7, 4), 512, 0, stream>>>(Pf2, Qpart, Rpart, Spart);
  finalize_kernel<<<256, 64, 0, stream>>>(C, Qpart, Rpart, Spart, yh, out);
}